// Round 3
// baseline (1080.313 us; speedup 1.0000x reference)
//
#include <hip/hip_runtime.h>

#define H 360
#define W 720
#define NB 8
#define TX 120
#define TY 45
#define GX 6           // 720/120
#define GY 8           // 360/45
#define BLK_PER_BATCH (GX*GY)   // 48
#define LSTRIDE 132    // LDS row stride (floats), 132*4=528 B, 16B-aligned
#define STEPS 20
#define DTS 600.0f
#define REARTH 6371000.0f
#define D2R 0.017453292519943295f

#define NQ1 (49*32)    // 1568 stage-1 load quads  (rows 0..48, 32 col-quads)
#define NQ2 (47*32)    // 1504 stage-2 advection quads (sT rows 1..47)
#define NQ3 (45*30)    // 1350 stage-3 output quads

__global__ __launch_bounds__(256, 2) void ocean_persist(
    const float* __restrict__ Tin, const float* __restrict__ ug,
    const float* __restrict__ vg, const float* __restrict__ lat,
    const float* __restrict__ lon, const float* __restrict__ mask,
    float* __restrict__ out, float* __restrict__ wsf, int* __restrict__ ctrs)
{
    __shared__ float sT[49 * LSTRIDE];   // T tile: rows gi=by-2+r, cols gj=bx-4+c (wrapped)
    __shared__ float sN[47 * LSTRIDE];   // post-advection: row r-1 of sT frame

    const int tid = threadIdx.x;
    const int b  = blockIdx.z;
    const int bx = blockIdx.x * TX;
    const int by = blockIdx.y * TY;
    const int plane = H * W;

    const float dlat = lat[1] - lat[0];               // -0.5
    const float dy   = REARTH * D2R * fabsf(dlat);
    const float sgn  = (dlat > 0.f) ? 1.f : -1.f;
    const float dlon = lon[1] - lon[0];
    const float i2dy = 0.5f / dy, i1dy = 1.f / dy;

    const float* Tb = Tin + b * plane;
    const float* ub = ug  + b * plane;
    const float* vb = vg  + b * plane;
    float* outb = out + b * plane;
    float* wsb  = wsf + b * plane;
    int* ctr = ctrs + b * 64;            // per-batch counter, 256 B apart

    // ---------- per-thread invariants (once) ----------
    int goff1[7], lds1o[7];
    #pragma unroll
    for (int k = 0; k < 7; ++k) {
        const int q = tid + 256 * k;
        if (q < NQ1) {
            const int r = q >> 5, c0 = (q & 31) << 2;
            int gi = by - 2 + r; gi = min(max(gi, 0), H - 1);
            int gj = (bx - 4 + c0 + W) % W;        // quad stays contiguous (mult of 4)
            goff1[k] = gi * W + gj;
            lds1o[k] = r * LSTRIDE + c0;
        } else goff1[k] = -1;
    }

    int ldsC[6], c0s[6];
    float cu[6][4], cv[6][4];
    unsigned dom = 0;
    #pragma unroll
    for (int k = 0; k < 6; ++k) {
        #pragma unroll
        for (int j = 0; j < 4; ++j) { cu[k][j] = 0.f; cv[k][j] = 0.f; }
        const int q = tid + 256 * k;
        if (q < NQ2) {
            const int r = 1 + (q >> 5), c0 = (q & 31) << 2;
            ldsC[k] = r * LSTRIDE + c0;
            c0s[k] = c0;
            const int gi = by - 2 + r;             // in [by-1, by+46)
            if ((unsigned)gi < H) {
                const float dxv  = REARTH * D2R * dlon * cosf(lat[gi] * D2R);
                const float rdx2 = 0.5f / dxv;
                const float ivy  = (gi == 0 || gi == H - 1) ? i1dy : i2dy;
                #pragma unroll
                for (int j = 0; j < 4; ++j) {
                    const int gj = bx - 4 + c0 + j;
                    if ((unsigned)gj < W) {
                        const int off = gi * W + gj;
                        const float mk = mask[off];
                        cu[k][j] = -DTS * mk * ub[off] * rdx2;
                        cv[k][j] = -DTS * mk * vb[off] * sgn * ivy;
                        dom |= 1u << (4 * k + j);
                    }
                }
            }
        } else ldsC[k] = -1;
    }

    int n3[6], o3[6];
    float m16[6][4];
    #pragma unroll
    for (int k = 0; k < 6; ++k) {
        const int q = tid + 256 * k;
        if (q < NQ3) {
            const int r = 1 + q / 30, qc = q % 30;
            const int c0 = 4 + 4 * qc;
            n3[k] = r * LSTRIDE + c0;
            const int gi = by + r - 1, gj = bx + 4 * qc;
            o3[k] = gi * W + gj;
            #pragma unroll
            for (int j = 0; j < 4; ++j) m16[k][j] = mask[gi * W + gj + j] * (1.f / 16.f);
        } else n3[k] = -1;
    }

    // ---------- 20 time steps ----------
    #pragma unroll 1
    for (int s = 0; s < STEPS; ++s) {
        if (s) {   // batch-scoped grid barrier (all 384 blocks resident: 2/CU cap)
            __syncthreads();
            if (tid == 0) {
                __threadfence();                                   // agent release (L2 wb)
                __hip_atomic_fetch_add(ctr, 1, __ATOMIC_RELEASE, __HIP_MEMORY_SCOPE_AGENT);
                const int tgt = s * BLK_PER_BATCH;
                long long t0 = (long long)clock64();
                while (__hip_atomic_load(ctr, __ATOMIC_ACQUIRE, __HIP_MEMORY_SCOPE_AGENT) < tgt) {
                    __builtin_amdgcn_s_sleep(8);
                    if ((long long)clock64() - t0 > 100000000LL) break;  // no-hang bailout
                }
                __threadfence();                                   // agent acquire (L1/L2 inv)
            }
            __syncthreads();
        }
        const float* cur = (s == 0) ? Tb : ((s & 1) ? wsb : outb);
        float* dst = (s & 1) ? outb : wsb;       // step 19 (odd) -> out

        // stage 1: global -> sT
        #pragma unroll
        for (int k = 0; k < 7; ++k)
            if (goff1[k] >= 0)
                *(float4*)(sT + lds1o[k]) = *(const float4*)(cur + goff1[k]);
        __syncthreads();

        // stage 2: advection -> sN (0 outside domain; W-wrap feeds dT_dx)
        #pragma unroll
        for (int k = 0; k < 6; ++k) {
            if (ldsC[k] < 0) continue;
            const int ci = ldsC[k];
            const float4 vC = *(const float4*)(sT + ci);
            const float4 vU = *(const float4*)(sT + ci - LSTRIDE);
            const float4 vD = *(const float4*)(sT + ci + LSTRIDE);
            const float l  = sT[c0s[k] ? ci - 1 : ci];               // garbage -> unread col
            const float rr = sT[(c0s[k] < 124) ? ci + 4 : ci + 3];   // garbage -> unread col
            float4 o;
            o.x = (((dom >> (4*k+0)) & 1) ? vC.x : 0.f) + cu[k][0]*(vC.y - l)    + cv[k][0]*(vD.x - vU.x);
            o.y = (((dom >> (4*k+1)) & 1) ? vC.y : 0.f) + cu[k][1]*(vC.z - vC.x) + cv[k][1]*(vD.y - vU.y);
            o.z = (((dom >> (4*k+2)) & 1) ? vC.z : 0.f) + cu[k][2]*(vC.w - vC.y) + cv[k][2]*(vD.z - vU.z);
            o.w = (((dom >> (4*k+3)) & 1) ? vC.w : 0.f) + cu[k][3]*(rr   - vC.z) + cv[k][3]*(vD.w - vU.w);
            *(float4*)(sN + ci - LSTRIDE) = o;
        }
        __syncthreads();

        // stage 3: 3x3 binomial (zero-padded via sN) * mask -> dst
        #pragma unroll
        for (int k = 0; k < 6; ++k) {
            if (n3[k] < 0) continue;
            const int ci = n3[k];
            float4 acc = {0.f, 0.f, 0.f, 0.f};
            #pragma unroll
            for (int dr = -1; dr <= 1; ++dr) {
                const int rbase = ci + dr * LSTRIDE;
                const float4 v = *(const float4*)(sN + rbase);
                const float l  = sN[rbase - 1];
                const float rr = sN[rbase + 4];
                const float w  = (dr == 0) ? 2.f : 1.f;
                acc.x += w * (l   + 2.f * v.x + v.y);
                acc.y += w * (v.x + 2.f * v.y + v.z);
                acc.z += w * (v.y + 2.f * v.z + v.w);
                acc.w += w * (v.z + 2.f * v.w + rr);
            }
            float4 o;
            o.x = acc.x * m16[k][0];
            o.y = acc.y * m16[k][1];
            o.z = acc.z * m16[k][2];
            o.w = acc.w * m16[k][3];
            *(float4*)(dst + o3[k]) = o;
        }
        // next barrier provides the post-store sync
    }
}

extern "C" void kernel_launch(void* const* d_in, const int* in_sizes, int n_in,
                              void* d_out, int out_size, void* d_ws, size_t ws_size,
                              hipStream_t stream)
{
    const float* T    = (const float*)d_in[0];
    const float* ug   = (const float*)d_in[1];
    const float* vg   = (const float*)d_in[2];
    const float* lat  = (const float*)d_in[3];
    const float* lon  = (const float*)d_in[4];
    const float* mask = (const float*)d_in[5];
    float* out = (float*)d_out;

    int*   ctrs = (int*)d_ws;                    // 8 counters @ 256 B stride
    float* wsf  = (float*)((char*)d_ws + 4096);  // ping-pong field (8.3 MB)

    hipMemsetAsync(d_ws, 0, 4096, stream);       // zero barrier counters (capture-legal)

    ocean_persist<<<dim3(GX, GY, NB), dim3(256), 0, stream>>>(
        T, ug, vg, lat, lon, mask, out, wsf, ctrs);
}

// Round 4
// 531.171 us; speedup vs baseline: 2.0338x; 2.0338x over previous
//
#include <hip/hip_runtime.h>

#define H 360
#define W 720
#define NB 8
#define TX 120
#define TY 45
#define GX 6
#define GY 8
#define BLK_PER_BATCH (GX*GY)   // 48
#define LSTRIDE 132             // LDS row stride (floats), 16B-aligned
#define STEPS 20
#define DTS 600.0f
#define REARTH 6371000.0f
#define D2R 0.017453292519943295f

#define NQ1 (49*32)    // 1568 stage-1 load quads  (sT rows 0..48, 32 col-quads)
#define NQ2 (47*32)    // 1504 stage-2 quads       (sT rows 1..47)
#define NQ3 (45*30)    // 1350 stage-3 output quads

__global__ __launch_bounds__(256, 2) void ocean_persist(
    const float* __restrict__ Tin, const float* __restrict__ ug,
    const float* __restrict__ vg, const float* __restrict__ lat,
    const float* __restrict__ lon, const float* __restrict__ mask,
    float* __restrict__ out, float* __restrict__ wsf, int* __restrict__ ctrs)
{
    __shared__ float sT[49 * LSTRIDE];   // T tile: gi=by-2+r (clamped), gj=bx-4+c (wrapped)
    __shared__ float sH[47 * LSTRIDE];   // horizontally-filtered advected field, row = sT row - 1

    const int tid = threadIdx.x;
    const int b  = blockIdx.z;
    const int bx = blockIdx.x * TX;
    const int by = blockIdx.y * TY;
    const int plane = H * W;

    const float dlat = lat[1] - lat[0];               // -0.5
    const float dy   = REARTH * D2R * fabsf(dlat);
    const float sgn  = (dlat > 0.f) ? 1.f : -1.f;
    const float dlon = lon[1] - lon[0];
    const float i2dy = 0.5f / dy, i1dy = 1.f / dy;

    const float* Tb = Tin + b * plane;
    const float* ub = ug  + b * plane;
    const float* vb = vg  + b * plane;
    float* outb = out + b * plane;
    float* wsb  = wsf + b * plane;
    int* ctr = ctrs + b * 64;            // per-batch counter, 256 B apart

    // ---------- per-thread invariants (once) ----------
    int goff1[7], lds1o[7];
    #pragma unroll
    for (int k = 0; k < 7; ++k) {
        const int q = tid + 256 * k;
        if (q < NQ1) {
            const int r = q >> 5, c0 = (q & 31) << 2;
            int gi = by - 2 + r; gi = min(max(gi, 0), H - 1);
            int gj = (bx - 4 + c0 + W) % W;        // whole-quad wrap (mult of 4)
            goff1[k] = gi * W + gj;
            lds1o[k] = r * LSTRIDE + c0;
        } else goff1[k] = -1;
    }

    int ldsC[6];
    float cu[6][4], cv[6][4];
    unsigned dom = 0;
    #pragma unroll
    for (int k = 0; k < 6; ++k) {
        #pragma unroll
        for (int j = 0; j < 4; ++j) { cu[k][j] = 0.f; cv[k][j] = 0.f; }
        const int q = tid + 256 * k;
        if (q < NQ2) {
            const int r = 1 + (q >> 5), c0 = (q & 31) << 2;
            ldsC[k] = r * LSTRIDE + c0;
            const int gi = by - 2 + r;
            if ((unsigned)gi < H) {
                const float dxv  = REARTH * D2R * dlon * cosf(lat[gi] * D2R);
                const float rdx2 = 0.5f / dxv;
                const float ivy  = (gi == 0 || gi == H - 1) ? i1dy : i2dy;
                #pragma unroll
                for (int j = 0; j < 4; ++j) {
                    const int gj = bx - 4 + c0 + j;
                    if ((unsigned)gj < W) {
                        const int off = gi * W + gj;
                        const float mk = mask[off];
                        cu[k][j] = -DTS * mk * ub[off] * rdx2;
                        cv[k][j] = -DTS * mk * vb[off] * sgn * ivy;
                        dom |= 1u << (4 * k + j);
                    }
                }
            }
        } else ldsC[k] = -1;
    }

    int n3[6], o3[6];
    float m16[6][4];
    #pragma unroll
    for (int k = 0; k < 6; ++k) {
        const int q = tid + 256 * k;
        if (q < NQ3) {
            const int r = 1 + q / 30, qc = q % 30;
            const int c0 = 4 + 4 * qc;
            n3[k] = r * LSTRIDE + c0;
            const int gi = by + r - 1, gj = bx + 4 * qc;
            o3[k] = gi * W + gj;
            #pragma unroll
            for (int j = 0; j < 4; ++j) m16[k][j] = mask[gi * W + gj + j] * (1.f / 16.f);
        } else n3[k] = -1;
    }

    // ---------- 20 time steps ----------
    #pragma unroll 1
    for (int s = 0; s < STEPS; ++s) {
        if (s) {   // batch-scoped barrier: RELEASE rmw, RELAXED spin, one ACQUIRE at exit
            __syncthreads();
            if (tid == 0) {
                __hip_atomic_fetch_add(ctr, 1, __ATOMIC_RELEASE, __HIP_MEMORY_SCOPE_AGENT);
                const int tgt = s * BLK_PER_BATCH;
                long long t0 = (long long)clock64();
                while (__hip_atomic_load(ctr, __ATOMIC_RELAXED, __HIP_MEMORY_SCOPE_AGENT) < tgt) {
                    __builtin_amdgcn_s_sleep(1);
                    if ((long long)clock64() - t0 > 200000000LL) break;  // no-hang bailout
                }
                (void)__hip_atomic_load(ctr, __ATOMIC_ACQUIRE, __HIP_MEMORY_SCOPE_AGENT);
            }
            __syncthreads();
        }
        const float* cur = (s == 0) ? Tb : ((s & 1) ? wsb : outb);
        float* dst = (s & 1) ? outb : wsb;       // step 19 (odd) -> out

        // stage 1: global -> sT (aligned float4)
        #pragma unroll
        for (int k = 0; k < 7; ++k)
            if (goff1[k] >= 0)
                *(float4*)(sT + lds1o[k]) = *(const float4*)(cur + goff1[k]);
        __syncthreads();

        // stage 2: advection + horizontal 1-2-1 pass -> sH
        // neighbor scalars come from cross-lane shuffles; lane-boundary garbage
        // only lands in window cols 0/127, outside the consumed range [3,124].
        #pragma unroll
        for (int k = 0; k < 6; ++k) {
            const bool act = (ldsC[k] >= 0);
            const int ci = act ? ldsC[k] : LSTRIDE;   // safe addr keeps wave converged
            const float4 vC = *(const float4*)(sT + ci);
            const float4 vU = *(const float4*)(sT + ci - LSTRIDE);
            const float4 vD = *(const float4*)(sT + ci + LSTRIDE);
            const float tl = __shfl_up(vC.w, 1);      // T at col c0-1
            const float tr = __shfl_down(vC.x, 1);    // T at col c0+4
            float4 o;
            o.x = (((dom >> (4*k+0)) & 1) ? vC.x : 0.f) + cu[k][0]*(vC.y - tl)   + cv[k][0]*(vD.x - vU.x);
            o.y = (((dom >> (4*k+1)) & 1) ? vC.y : 0.f) + cu[k][1]*(vC.z - vC.x) + cv[k][1]*(vD.y - vU.y);
            o.z = (((dom >> (4*k+2)) & 1) ? vC.z : 0.f) + cu[k][2]*(vC.w - vC.y) + cv[k][2]*(vD.z - vU.z);
            o.w = (((dom >> (4*k+3)) & 1) ? vC.w : 0.f) + cu[k][3]*(tr   - vC.z) + cv[k][3]*(vD.w - vU.w);
            const float hl = __shfl_up(o.w, 1);
            const float hr = __shfl_down(o.x, 1);
            float4 h;
            h.x = hl  + 2.f * o.x + o.y;
            h.y = o.x + 2.f * o.y + o.z;
            h.z = o.y + 2.f * o.z + o.w;
            h.w = o.z + 2.f * o.w + hr;
            if (act) *(float4*)(sH + ci - LSTRIDE) = h;
        }
        __syncthreads();

        // stage 3: vertical 1-2-1 pass (all aligned float4 reads) * mask -> dst
        #pragma unroll
        for (int k = 0; k < 6; ++k) {
            if (n3[k] < 0) continue;
            const int ci = n3[k];
            const float4 a = *(const float4*)(sH + ci - LSTRIDE);
            const float4 m = *(const float4*)(sH + ci);
            const float4 c = *(const float4*)(sH + ci + LSTRIDE);
            float4 o;
            o.x = (a.x + 2.f * m.x + c.x) * m16[k][0];
            o.y = (a.y + 2.f * m.y + c.y) * m16[k][1];
            o.z = (a.z + 2.f * m.z + c.z) * m16[k][2];
            o.w = (a.w + 2.f * m.w + c.w) * m16[k][3];
            *(float4*)(dst + o3[k]) = o;
        }
        // next barrier provides the post-store sync
    }
}

extern "C" void kernel_launch(void* const* d_in, const int* in_sizes, int n_in,
                              void* d_out, int out_size, void* d_ws, size_t ws_size,
                              hipStream_t stream)
{
    const float* T    = (const float*)d_in[0];
    const float* ug   = (const float*)d_in[1];
    const float* vg   = (const float*)d_in[2];
    const float* lat  = (const float*)d_in[3];
    const float* lon  = (const float*)d_in[4];
    const float* mask = (const float*)d_in[5];
    float* out = (float*)d_out;

    int*   ctrs = (int*)d_ws;                    // 8 counters @ 256 B stride
    float* wsf  = (float*)((char*)d_ws + 4096);  // ping-pong field (8.3 MB)

    hipMemsetAsync(d_ws, 0, 4096, stream);       // zero barrier counters (capture-legal)

    ocean_persist<<<dim3(GX, GY, NB), dim3(256), 0, stream>>>(
        T, ug, vg, lat, lon, mask, out, wsf, ctrs);
}

// Round 5
// 341.626 us; speedup vs baseline: 3.1623x; 1.5548x over previous
//
#include <hip/hip_runtime.h>

#define H 360
#define W 720
#define NB 8
#define TX 120
#define TY 45
#define GX 6
#define GY 8
#define BLK_PER_BATCH (GX*GY)   // 48
#define LSTRIDE 132             // LDS row stride (floats), 16B-aligned
#define STEPS 20
#define DTS 600.0f
#define REARTH 6371000.0f
#define D2R 0.017453292519943295f

#define NQ1 (49*32)    // 1568 stage-1 load quads  (sT rows 0..48, 32 col-quads)
#define NQ2 (47*32)    // 1504 stage-2 quads       (sT rows 1..47)
#define NQ3 (45*30)    // 1350 stage-3 output quads

// Device-coherent 8B load/store: agent-scope RELAXED atomics lower to plain
// global_load/store_dwordx2 with sc1 (LLC-coherent) -- NO buffer_wbl2/inv.
static __device__ __forceinline__ float2 ldc8(const float* p) {
    unsigned long long u = __hip_atomic_load((const unsigned long long*)p,
                                             __ATOMIC_RELAXED, __HIP_MEMORY_SCOPE_AGENT);
    return __builtin_bit_cast(float2, u);
}
static __device__ __forceinline__ void stc8(float* p, float2 v) {
    __hip_atomic_store((unsigned long long*)p, __builtin_bit_cast(unsigned long long, v),
                       __ATOMIC_RELAXED, __HIP_MEMORY_SCOPE_AGENT);
}

__global__ __launch_bounds__(256, 2) void ocean_persist(
    const float* __restrict__ Tin, const float* __restrict__ ug,
    const float* __restrict__ vg, const float* __restrict__ lat,
    const float* __restrict__ lon, const float* __restrict__ mask,
    float* __restrict__ out, float* __restrict__ wsf, int* __restrict__ ctrs)
{
    __shared__ float sT[49 * LSTRIDE];   // T tile: gi=by-2+r (clamped), gj=bx-4+c (wrapped)
    __shared__ float sH[47 * LSTRIDE];   // horizontally-filtered advected field

    const int tid = threadIdx.x;
    const int b  = blockIdx.z;
    const int bx = blockIdx.x * TX;
    const int by = blockIdx.y * TY;
    const int plane = H * W;

    const float dlat = lat[1] - lat[0];               // -0.5
    const float dy   = REARTH * D2R * fabsf(dlat);
    const float sgn  = (dlat > 0.f) ? 1.f : -1.f;
    const float dlon = lon[1] - lon[0];
    const float i2dy = 0.5f / dy, i1dy = 1.f / dy;

    const float* Tb = Tin + b * plane;
    const float* ub = ug  + b * plane;
    const float* vb = vg  + b * plane;
    float* outb = out + b * plane;
    float* wsb  = wsf + b * plane;
    int* ctr = ctrs + b * 64;            // per-batch counter, 256 B apart

    // ---------- per-thread invariants (once; normal cached loads) ----------
    int goff1[7], lds1o[7];
    #pragma unroll
    for (int k = 0; k < 7; ++k) {
        const int q = tid + 256 * k;
        if (q < NQ1) {
            const int r = q >> 5, c0 = (q & 31) << 2;
            int gi = by - 2 + r; gi = min(max(gi, 0), H - 1);
            int gj = (bx - 4 + c0 + W) % W;        // whole-quad wrap (mult of 4)
            goff1[k] = gi * W + gj;
            lds1o[k] = r * LSTRIDE + c0;
        } else goff1[k] = -1;
    }

    int ldsC[6];
    float cu[6][4], cv[6][4];
    unsigned dom = 0;
    #pragma unroll
    for (int k = 0; k < 6; ++k) {
        #pragma unroll
        for (int j = 0; j < 4; ++j) { cu[k][j] = 0.f; cv[k][j] = 0.f; }
        const int q = tid + 256 * k;
        if (q < NQ2) {
            const int r = 1 + (q >> 5), c0 = (q & 31) << 2;
            ldsC[k] = r * LSTRIDE + c0;
            const int gi = by - 2 + r;
            if ((unsigned)gi < H) {
                const float dxv  = REARTH * D2R * dlon * cosf(lat[gi] * D2R);
                const float rdx2 = 0.5f / dxv;
                const float ivy  = (gi == 0 || gi == H - 1) ? i1dy : i2dy;
                #pragma unroll
                for (int j = 0; j < 4; ++j) {
                    const int gj = bx - 4 + c0 + j;
                    if ((unsigned)gj < W) {
                        const int off = gi * W + gj;
                        const float mk = mask[off];
                        cu[k][j] = -DTS * mk * ub[off] * rdx2;
                        cv[k][j] = -DTS * mk * vb[off] * sgn * ivy;
                        dom |= 1u << (4 * k + j);
                    }
                }
            }
        } else ldsC[k] = -1;
    }

    int n3[6], o3[6];
    float m16[6][4];
    #pragma unroll
    for (int k = 0; k < 6; ++k) {
        const int q = tid + 256 * k;
        if (q < NQ3) {
            const int r = 1 + q / 30, qc = q % 30;
            const int c0 = 4 + 4 * qc;
            n3[k] = r * LSTRIDE + c0;
            const int gi = by + r - 1, gj = bx + 4 * qc;
            o3[k] = gi * W + gj;
            #pragma unroll
            for (int j = 0; j < 4; ++j) m16[k][j] = mask[gi * W + gj + j] * (1.f / 16.f);
        } else n3[k] = -1;
    }

    // ---------- 20 time steps ----------
    #pragma unroll 1
    for (int s = 0; s < STEPS; ++s) {
        if (s) {
            // All sc1 stores were drained by the pre-barrier vmcnt(0) that
            // __syncthreads() implies (acked at the coherence point), so the
            // barrier is pure RELAXED arithmetic: no wbl2 / no inv anywhere.
            __syncthreads();
            if (tid == 0) {
                __hip_atomic_fetch_add(ctr, 1, __ATOMIC_RELAXED, __HIP_MEMORY_SCOPE_AGENT);
                const int tgt = s * BLK_PER_BATCH;
                long long t0 = (long long)clock64();
                while (__hip_atomic_load(ctr, __ATOMIC_RELAXED, __HIP_MEMORY_SCOPE_AGENT) < tgt) {
                    __builtin_amdgcn_s_sleep(1);
                    if ((long long)clock64() - t0 > 200000000LL) break;  // no-hang bailout
                }
            }
            __syncthreads();
        }
        const float* cur = (s == 0) ? Tb : ((s & 1) ? wsb : outb);
        float* dst = (s & 1) ? outb : wsb;       // step 19 (odd) -> out

        // stage 1: global (LLC-coherent 8B) -> sT (aligned b128 writes)
        #pragma unroll
        for (int k = 0; k < 7; ++k)
            if (goff1[k] >= 0) {
                const float2 lo = ldc8(cur + goff1[k]);
                const float2 hi = ldc8(cur + goff1[k] + 2);
                float4 v; v.x = lo.x; v.y = lo.y; v.z = hi.x; v.w = hi.y;
                *(float4*)(sT + lds1o[k]) = v;
            }
        __syncthreads();

        // stage 2: advection + horizontal 1-2-1 pass -> sH (shuffle neighbors;
        // lane-boundary garbage only lands in window cols 0/127, never consumed)
        #pragma unroll
        for (int k = 0; k < 6; ++k) {
            const bool act = (ldsC[k] >= 0);
            const int ci = act ? ldsC[k] : LSTRIDE;   // safe addr keeps wave converged
            const float4 vC = *(const float4*)(sT + ci);
            const float4 vU = *(const float4*)(sT + ci - LSTRIDE);
            const float4 vD = *(const float4*)(sT + ci + LSTRIDE);
            const float tl = __shfl_up(vC.w, 1);
            const float tr = __shfl_down(vC.x, 1);
            float4 o;
            o.x = (((dom >> (4*k+0)) & 1) ? vC.x : 0.f) + cu[k][0]*(vC.y - tl)   + cv[k][0]*(vD.x - vU.x);
            o.y = (((dom >> (4*k+1)) & 1) ? vC.y : 0.f) + cu[k][1]*(vC.z - vC.x) + cv[k][1]*(vD.y - vU.y);
            o.z = (((dom >> (4*k+2)) & 1) ? vC.z : 0.f) + cu[k][2]*(vC.w - vC.y) + cv[k][2]*(vD.z - vU.z);
            o.w = (((dom >> (4*k+3)) & 1) ? vC.w : 0.f) + cu[k][3]*(tr   - vC.z) + cv[k][3]*(vD.w - vU.w);
            const float hl = __shfl_up(o.w, 1);
            const float hr = __shfl_down(o.x, 1);
            float4 h;
            h.x = hl  + 2.f * o.x + o.y;
            h.y = o.x + 2.f * o.y + o.z;
            h.z = o.y + 2.f * o.z + o.w;
            h.w = o.z + 2.f * o.w + hr;
            if (act) *(float4*)(sH + ci - LSTRIDE) = h;
        }
        __syncthreads();

        // stage 3: vertical 1-2-1 (aligned b128 reads) * mask -> dst (sc1 8B)
        #pragma unroll
        for (int k = 0; k < 6; ++k) {
            if (n3[k] < 0) continue;
            const int ci = n3[k];
            const float4 a = *(const float4*)(sH + ci - LSTRIDE);
            const float4 m = *(const float4*)(sH + ci);
            const float4 c = *(const float4*)(sH + ci + LSTRIDE);
            float2 lo, hi;
            lo.x = (a.x + 2.f * m.x + c.x) * m16[k][0];
            lo.y = (a.y + 2.f * m.y + c.y) * m16[k][1];
            hi.x = (a.z + 2.f * m.z + c.z) * m16[k][2];
            hi.y = (a.w + 2.f * m.w + c.w) * m16[k][3];
            stc8(dst + o3[k], lo);
            stc8(dst + o3[k] + 2, hi);
        }
        // next barrier's __syncthreads drains these stores (vmcnt ack @ LLC)
    }
}

extern "C" void kernel_launch(void* const* d_in, const int* in_sizes, int n_in,
                              void* d_out, int out_size, void* d_ws, size_t ws_size,
                              hipStream_t stream)
{
    const float* T    = (const float*)d_in[0];
    const float* ug   = (const float*)d_in[1];
    const float* vg   = (const float*)d_in[2];
    const float* lat  = (const float*)d_in[3];
    const float* lon  = (const float*)d_in[4];
    const float* mask = (const float*)d_in[5];
    float* out = (float*)d_out;

    int*   ctrs = (int*)d_ws;                    // 8 counters @ 256 B stride
    float* wsf  = (float*)((char*)d_ws + 4096);  // ping-pong field (8.3 MB)

    hipMemsetAsync(d_ws, 0, 4096, stream);       // zero barrier counters (capture-legal)

    ocean_persist<<<dim3(GX, GY, NB), dim3(256), 0, stream>>>(
        T, ug, vg, lat, lon, mask, out, wsf, ctrs);
}

// Round 6
// 280.108 us; speedup vs baseline: 3.8568x; 1.2196x over previous
//
#include <hip/hip_runtime.h>

#define H 360
#define W 720
#define NB 8
#define TX 120
#define TY 45
#define GX 6
#define GY 8
#define BPB 48                  // blocks per batch
#define LSTRIDE 132             // LDS row stride (floats), 16B-aligned
#define STEPS 20
#define DTS 600.0f
#define REARTH 6371000.0f
#define D2R 0.017453292519943295f

#define NQ1 (49*32)    // 1568 preamble load quads (sT rows 0..48 x 32 col-quads)
#define NQ2 (47*32)    // 1504 stage-2 quads (sT rows 1..47)
#define NQ3 (45*30)    // 1350 stage-3 tile quads
#define NHALO 218      // per-step halo quads: 4 rows x 32 + 45 rows x 2 cols

// LLC-coherent 8B load/store (agent-scope relaxed atomic -> plain dwordx2 sc1,
// no buffer_wbl2/buffer_inv anywhere in the loop).
static __device__ __forceinline__ float2 ldc8(const float* p) {
    unsigned long long u = __hip_atomic_load((const unsigned long long*)p,
                                             __ATOMIC_RELAXED, __HIP_MEMORY_SCOPE_AGENT);
    return __builtin_bit_cast(float2, u);
}
static __device__ __forceinline__ void stc8(float* p, float2 v) {
    __hip_atomic_store((unsigned long long*)p, __builtin_bit_cast(unsigned long long, v),
                       __ATOMIC_RELAXED, __HIP_MEMORY_SCOPE_AGENT);
}

__global__ __launch_bounds__(256, 2) void ocean_persist(
    const float* __restrict__ Tin, const float* __restrict__ ug,
    const float* __restrict__ vg, const float* __restrict__ lat,
    const float* __restrict__ lon, const float* __restrict__ mask,
    float* __restrict__ out, float* __restrict__ wsf, int* __restrict__ ctrs)
{
    __shared__ float sT[49 * LSTRIDE];   // persistent T tile: gi=by-2+r, gj=bx-4+c
    __shared__ float sH[47 * LSTRIDE];   // horizontally-filtered advected field

    const int tid = threadIdx.x;
    const int b  = blockIdx.z;
    const int bx = blockIdx.x * TX;
    const int by = blockIdx.y * TY;
    const int plane = H * W;

    const float dlat = lat[1] - lat[0];               // -0.5
    const float dy   = REARTH * D2R * fabsf(dlat);
    const float sgn  = (dlat > 0.f) ? 1.f : -1.f;
    const float dlon = lon[1] - lon[0];
    const float i2dy = 0.5f / dy, i1dy = 1.f / dy;

    const float* Tb = Tin + b * plane;
    const float* ub = ug  + b * plane;
    const float* vb = vg  + b * plane;
    float* outb = out + b * plane;
    float* wsb  = wsf + b * plane;
    int* ctr = ctrs + b * 64;            // per-batch counter, 256 B apart

    // ---------- per-thread invariants (once; cached loads) ----------
    int goff1[7], lds1o[7];              // preamble: full tile+halo
    #pragma unroll
    for (int k = 0; k < 7; ++k) {
        const int q = tid + 256 * k;
        if (q < NQ1) {
            const int r = q >> 5, c0 = (q & 31) << 2;
            int gi = by - 2 + r; gi = min(max(gi, 0), H - 1);
            int gj = (bx - 4 + c0 + W) % W;
            goff1[k] = gi * W + gj;
            lds1o[k] = r * LSTRIDE + c0;
        } else goff1[k] = -1;
    }

    int hgo = -1, hlo = 0;               // per-step halo quad (1 per thread)
    if (tid < NHALO) {
        int r, c0;
        if (tid < 128) {                 // full-width row strips r in {0,1,47,48}
            const int ri = tid >> 5;
            r  = (ri < 2) ? ri : (45 + ri);      // 0,1,47,48
            c0 = (tid & 31) << 2;
        } else {                         // col strips r=2..46, c0 in {0,124}
            const int t = tid - 128;
            r  = 2 + (t >> 1);
            c0 = (t & 1) ? 124 : 0;
        }
        int gi = by - 2 + r; gi = min(max(gi, 0), H - 1);
        int gj = (bx - 4 + c0 + W) % W;
        hgo = gi * W + gj;
        hlo = r * LSTRIDE + c0;
    }

    int ldsC[6];
    float cu[6][4], cv[6][4];
    unsigned dom = 0;
    #pragma unroll
    for (int k = 0; k < 6; ++k) {
        #pragma unroll
        for (int j = 0; j < 4; ++j) { cu[k][j] = 0.f; cv[k][j] = 0.f; }
        const int q = tid + 256 * k;
        if (q < NQ2) {
            const int r = 1 + (q >> 5), c0 = (q & 31) << 2;
            ldsC[k] = r * LSTRIDE + c0;
            const int gi = by - 2 + r;
            if ((unsigned)gi < H) {
                const float dxv  = REARTH * D2R * dlon * cosf(lat[gi] * D2R);
                const float rdx2 = 0.5f / dxv;
                const float ivy  = (gi == 0 || gi == H - 1) ? i1dy : i2dy;
                #pragma unroll
                for (int j = 0; j < 4; ++j) {
                    const int gj = bx - 4 + c0 + j;
                    if ((unsigned)gj < W) {
                        const int off = gi * W + gj;
                        const float mk = mask[off];
                        cu[k][j] = -DTS * mk * ub[off] * rdx2;
                        cv[k][j] = -DTS * mk * vb[off] * sgn * ivy;
                        dom |= 1u << (4 * k + j);
                    }
                }
            }
        } else ldsC[k] = -1;
    }

    int n3[6], o3[6];
    float m16[6][4];
    unsigned ring3 = 0;                  // quads within 2 of tile boundary
    #pragma unroll
    for (int k = 0; k < 6; ++k) {
        const int q = tid + 256 * k;
        if (q < NQ3) {
            const int tr = q / 30, qc = q % 30;    // tile row 0..44, col-quad 0..29
            const int r = 1 + tr;
            const int c0 = 4 + 4 * qc;
            n3[k] = r * LSTRIDE + c0;
            const int gi = by + tr, gj = bx + 4 * qc;
            o3[k] = gi * W + gj;
            if (tr < 2 || tr > 42 || qc == 0 || qc == 29) ring3 |= 1u << k;
            #pragma unroll
            for (int j = 0; j < 4; ++j) m16[k][j] = mask[gi * W + gj + j] * (1.f / 16.f);
        } else n3[k] = -1;
    }

    // ---------- preamble: full tile+halo -> sT (cached float4) ----------
    #pragma unroll
    for (int k = 0; k < 7; ++k)
        if (goff1[k] >= 0)
            *(float4*)(sT + lds1o[k]) = *(const float4*)(Tb + goff1[k]);
    __syncthreads();

    // ---------- 20 time steps; T stays resident in sT ----------
    #pragma unroll 1
    for (int s = 0; s < STEPS; ++s) {
        if (s) {
            // batch-scoped barrier: all relaxed (stores already drained by the
            // vmcnt(0) each wave executes before s_barrier in __syncthreads)
            __syncthreads();
            if (tid == 0) {
                __hip_atomic_fetch_add(ctr, 1, __ATOMIC_RELAXED, __HIP_MEMORY_SCOPE_AGENT);
                const int tgt = s * BPB;
                long long t0 = (long long)clock64();
                while (__hip_atomic_load(ctr, __ATOMIC_RELAXED, __HIP_MEMORY_SCOPE_AGENT) < tgt) {
                    __builtin_amdgcn_s_sleep(1);
                    if ((long long)clock64() - t0 > 200000000LL) break;  // no-hang bailout
                }
            }
            __syncthreads();
            // stage 1: halo-only refresh from prev ring buffer (sc1)
            const float* prev = (s & 1) ? wsb : outb;   // ring(s-1) lives in buf[(s-1)&1]
            if (hgo >= 0) {
                const float2 lo = ldc8(prev + hgo);
                const float2 hi = ldc8(prev + hgo + 2);
                float4 v; v.x = lo.x; v.y = lo.y; v.z = hi.x; v.w = hi.y;
                *(float4*)(sT + hlo) = v;
            }
            __syncthreads();
        }

        // stage 2: advection + horizontal 1-2-1 -> sH (shuffle neighbors)
        #pragma unroll
        for (int k = 0; k < 6; ++k) {
            const bool act = (ldsC[k] >= 0);
            const int ci = act ? ldsC[k] : LSTRIDE;
            const float4 vC = *(const float4*)(sT + ci);
            const float4 vU = *(const float4*)(sT + ci - LSTRIDE);
            const float4 vD = *(const float4*)(sT + ci + LSTRIDE);
            const float tl = __shfl_up(vC.w, 1);
            const float tr = __shfl_down(vC.x, 1);
            float4 o;
            o.x = (((dom >> (4*k+0)) & 1) ? vC.x : 0.f) + cu[k][0]*(vC.y - tl)   + cv[k][0]*(vD.x - vU.x);
            o.y = (((dom >> (4*k+1)) & 1) ? vC.y : 0.f) + cu[k][1]*(vC.z - vC.x) + cv[k][1]*(vD.y - vU.y);
            o.z = (((dom >> (4*k+2)) & 1) ? vC.z : 0.f) + cu[k][2]*(vC.w - vC.y) + cv[k][2]*(vD.z - vU.z);
            o.w = (((dom >> (4*k+3)) & 1) ? vC.w : 0.f) + cu[k][3]*(tr   - vC.z) + cv[k][3]*(vD.w - vU.w);
            const float hl = __shfl_up(o.w, 1);
            const float hr = __shfl_down(o.x, 1);
            float4 h;
            h.x = hl  + 2.f * o.x + o.y;
            h.y = o.x + 2.f * o.y + o.z;
            h.z = o.y + 2.f * o.z + o.w;
            h.w = o.z + 2.f * o.w + hr;
            if (act) *(float4*)(sH + ci - LSTRIDE) = h;
        }
        __syncthreads();

        // stage 3: vertical 1-2-1 * mask; write back into sT + export ring
        float* rcur = (s & 1) ? outb : wsb;     // ring(s) -> buf[s&1]
        #pragma unroll
        for (int k = 0; k < 6; ++k) {
            if (n3[k] < 0) continue;
            const int ci = n3[k];
            const float4 a = *(const float4*)(sH + ci - LSTRIDE);
            const float4 m = *(const float4*)(sH + ci);
            const float4 c = *(const float4*)(sH + ci + LSTRIDE);
            float4 o;
            o.x = (a.x + 2.f * m.x + c.x) * m16[k][0];
            o.y = (a.y + 2.f * m.y + c.y) * m16[k][1];
            o.z = (a.z + 2.f * m.z + c.z) * m16[k][2];
            o.w = (a.w + 2.f * m.w + c.w) * m16[k][3];
            if (s < STEPS - 1) {
                *(float4*)(sT + ci + LSTRIDE) = o;           // keep tile in LDS
                if ((ring3 >> k) & 1) {                      // export boundary ring
                    float2 lo; lo.x = o.x; lo.y = o.y;
                    float2 hi; hi.x = o.z; hi.y = o.w;
                    stc8(rcur + o3[k], lo);
                    stc8(rcur + o3[k] + 2, hi);
                }
            } else {
                *(float4*)(outb + o3[k]) = o;                // final: plain cached store
            }
        }
        // next barrier's __syncthreads drains ring stores (vmcnt ack @ LLC)
    }
}

extern "C" void kernel_launch(void* const* d_in, const int* in_sizes, int n_in,
                              void* d_out, int out_size, void* d_ws, size_t ws_size,
                              hipStream_t stream)
{
    const float* T    = (const float*)d_in[0];
    const float* ug   = (const float*)d_in[1];
    const float* vg   = (const float*)d_in[2];
    const float* lat  = (const float*)d_in[3];
    const float* lon  = (const float*)d_in[4];
    const float* mask = (const float*)d_in[5];
    float* out = (float*)d_out;

    int*   ctrs = (int*)d_ws;                    // 8 counters @ 256 B stride
    float* wsf  = (float*)((char*)d_ws + 4096);  // even-step ring buffer (8.3 MB)

    hipMemsetAsync(d_ws, 0, 4096, stream);       // zero barrier counters (capture-legal)

    ocean_persist<<<dim3(GX, GY, NB), dim3(256), 0, stream>>>(
        T, ug, vg, lat, lon, mask, out, wsf, ctrs);
}

// Round 7
// 238.160 us; speedup vs baseline: 4.5361x; 1.1761x over previous
//
#include <hip/hip_runtime.h>

#define H 360
#define W 720
#define NB 8
#define TX 120
#define TY 45
#define GX 6
#define GY 8
#define BPB 48                  // blocks per batch
#define LSTRIDE 132             // LDS row stride (floats), 16B-aligned
#define STEPS 20
#define DTS 600.0f
#define REARTH 6371000.0f
#define D2R 0.017453292519943295f

#define NQ1 (49*32)    // 1568 preamble load quads (sT rows 0..48 x 32 col-quads)
#define NQ2 (47*32)    // 1504 stage-2 quads (sT rows 1..47)
#define NQ3 (45*30)    // 1350 stage-3 tile quads
#define NHALO 218      // per-step halo quads: 4 rows x 32 + 45 rows x 2 cols

#define FLAG_STRIDE 32          // ints: 128 B -> one flag per LLC line
#define FLAG_REGION (NB*BPB*FLAG_STRIDE*4)   // 49152 B

// LLC-coherent 8B load/store (agent-scope relaxed atomic -> plain dwordx2 sc1,
// no buffer_wbl2/buffer_inv anywhere in the loop).
static __device__ __forceinline__ float2 ldc8(const float* p) {
    unsigned long long u = __hip_atomic_load((const unsigned long long*)p,
                                             __ATOMIC_RELAXED, __HIP_MEMORY_SCOPE_AGENT);
    return __builtin_bit_cast(float2, u);
}
static __device__ __forceinline__ void stc8(float* p, float2 v) {
    __hip_atomic_store((unsigned long long*)p, __builtin_bit_cast(unsigned long long, v),
                       __ATOMIC_RELAXED, __HIP_MEMORY_SCOPE_AGENT);
}

__global__ __launch_bounds__(256, 2) void ocean_persist(
    const float* __restrict__ Tin, const float* __restrict__ ug,
    const float* __restrict__ vg, const float* __restrict__ lat,
    const float* __restrict__ lon, const float* __restrict__ mask,
    float* __restrict__ out, float* __restrict__ wsf, int* __restrict__ flags)
{
    __shared__ float sT[49 * LSTRIDE];   // persistent T tile: gi=by-2+r, gj=bx-4+c
    __shared__ float sH[47 * LSTRIDE];   // horizontally-filtered advected field

    const int tid = threadIdx.x;
    const int b  = blockIdx.z;
    const int bx = blockIdx.x * TX;
    const int by = blockIdx.y * TY;
    const int plane = H * W;

    const float dlat = lat[1] - lat[0];               // -0.5
    const float dy   = REARTH * D2R * fabsf(dlat);
    const float sgn  = (dlat > 0.f) ? 1.f : -1.f;
    const float dlon = lon[1] - lon[0];
    const float i2dy = 0.5f / dy, i1dy = 1.f / dy;

    const float* Tb = Tin + b * plane;
    const float* ub = ug  + b * plane;
    const float* vb = vg  + b * plane;
    float* outb = out + b * plane;
    float* wsb  = wsf + b * plane;

    int* bflags = flags + b * BPB * FLAG_STRIDE;          // this batch's 48 flags
    int* myflag = bflags + (blockIdx.y * GX + blockIdx.x) * FLAG_STRIDE;

    // ---------- per-thread invariants (once; cached loads) ----------
    int goff1[7], lds1o[7];              // preamble: full tile+halo
    #pragma unroll
    for (int k = 0; k < 7; ++k) {
        const int q = tid + 256 * k;
        if (q < NQ1) {
            const int r = q >> 5, c0 = (q & 31) << 2;
            int gi = by - 2 + r; gi = min(max(gi, 0), H - 1);
            int gj = (bx - 4 + c0 + W) % W;
            goff1[k] = gi * W + gj;
            lds1o[k] = r * LSTRIDE + c0;
        } else goff1[k] = -1;
    }

    int hgo = -1, hlo = 0;               // per-step halo quad (1 per thread)
    if (tid < NHALO) {
        int r, c0;
        if (tid < 128) {                 // full-width row strips r in {0,1,47,48}
            const int ri = tid >> 5;
            r  = (ri < 2) ? ri : (45 + ri);      // 0,1,47,48
            c0 = (tid & 31) << 2;
        } else {                         // col strips r=2..46, c0 in {0,124}
            const int t = tid - 128;
            r  = 2 + (t >> 1);
            c0 = (t & 1) ? 124 : 0;
        }
        int gi = by - 2 + r; gi = min(max(gi, 0), H - 1);
        int gj = (bx - 4 + c0 + W) % W;
        hgo = gi * W + gj;
        hlo = r * LSTRIDE + c0;
    }

    int ldsC[6];
    float cu[6][4], cv[6][4];
    unsigned dom = 0;
    #pragma unroll
    for (int k = 0; k < 6; ++k) {
        #pragma unroll
        for (int j = 0; j < 4; ++j) { cu[k][j] = 0.f; cv[k][j] = 0.f; }
        const int q = tid + 256 * k;
        if (q < NQ2) {
            const int r = 1 + (q >> 5), c0 = (q & 31) << 2;
            ldsC[k] = r * LSTRIDE + c0;
            const int gi = by - 2 + r;
            if ((unsigned)gi < H) {
                const float dxv  = REARTH * D2R * dlon * cosf(lat[gi] * D2R);
                const float rdx2 = 0.5f / dxv;
                const float ivy  = (gi == 0 || gi == H - 1) ? i1dy : i2dy;
                #pragma unroll
                for (int j = 0; j < 4; ++j) {
                    const int gj = bx - 4 + c0 + j;
                    if ((unsigned)gj < W) {
                        const int off = gi * W + gj;
                        const float mk = mask[off];
                        cu[k][j] = -DTS * mk * ub[off] * rdx2;
                        cv[k][j] = -DTS * mk * vb[off] * sgn * ivy;
                        dom |= 1u << (4 * k + j);
                    }
                }
            }
        } else ldsC[k] = -1;
    }

    int n3[6], o3[6];
    float m16[6][4];
    unsigned ring3 = 0;                  // quads within 2 of tile boundary
    #pragma unroll
    for (int k = 0; k < 6; ++k) {
        const int q = tid + 256 * k;
        if (q < NQ3) {
            const int tr = q / 30, qc = q % 30;    // tile row 0..44, col-quad 0..29
            const int r = 1 + tr;
            const int c0 = 4 + 4 * qc;
            n3[k] = r * LSTRIDE + c0;
            const int gi = by + tr, gj = bx + 4 * qc;
            o3[k] = gi * W + gj;
            if (tr < 2 || tr > 42 || qc == 0 || qc == 29) ring3 |= 1u << k;
            #pragma unroll
            for (int j = 0; j < 4; ++j) m16[k][j] = mask[gi * W + gj + j] * (1.f / 16.f);
        } else n3[k] = -1;
    }

    // ---------- preamble: full tile+halo -> sT (cached float4) ----------
    #pragma unroll
    for (int k = 0; k < 7; ++k)
        if (goff1[k] >= 0)
            *(float4*)(sT + lds1o[k]) = *(const float4*)(Tb + goff1[k]);
    __syncthreads();

    // ---------- 20 time steps; T stays resident in sT ----------
    #pragma unroll 1
    for (int s = 0; s < STEPS; ++s) {
        // stage 2: advection + horizontal 1-2-1 -> sH (shuffle neighbors;
        // lane-boundary garbage only lands in window cols 0/127, never consumed)
        #pragma unroll
        for (int k = 0; k < 6; ++k) {
            const bool act = (ldsC[k] >= 0);
            const int ci = act ? ldsC[k] : LSTRIDE;
            const float4 vC = *(const float4*)(sT + ci);
            const float4 vU = *(const float4*)(sT + ci - LSTRIDE);
            const float4 vD = *(const float4*)(sT + ci + LSTRIDE);
            const float tl = __shfl_up(vC.w, 1);
            const float tr = __shfl_down(vC.x, 1);
            float4 o;
            o.x = (((dom >> (4*k+0)) & 1) ? vC.x : 0.f) + cu[k][0]*(vC.y - tl)   + cv[k][0]*(vD.x - vU.x);
            o.y = (((dom >> (4*k+1)) & 1) ? vC.y : 0.f) + cu[k][1]*(vC.z - vC.x) + cv[k][1]*(vD.y - vU.y);
            o.z = (((dom >> (4*k+2)) & 1) ? vC.z : 0.f) + cu[k][2]*(vC.w - vC.y) + cv[k][2]*(vD.z - vU.z);
            o.w = (((dom >> (4*k+3)) & 1) ? vC.w : 0.f) + cu[k][3]*(tr   - vC.z) + cv[k][3]*(vD.w - vU.w);
            const float hl = __shfl_up(o.w, 1);
            const float hr = __shfl_down(o.x, 1);
            float4 h;
            h.x = hl  + 2.f * o.x + o.y;
            h.y = o.x + 2.f * o.y + o.z;
            h.z = o.y + 2.f * o.z + o.w;
            h.w = o.z + 2.f * o.w + hr;
            if (act) *(float4*)(sH + ci - LSTRIDE) = h;
        }
        __syncthreads();

        // stage 3: vertical 1-2-1 * mask; write back into sT + export ring
        float* rcur = (s & 1) ? outb : wsb;     // ring(s) -> buf[s&1]
        #pragma unroll
        for (int k = 0; k < 6; ++k) {
            if (n3[k] < 0) continue;
            const int ci = n3[k];
            const float4 a = *(const float4*)(sH + ci - LSTRIDE);
            const float4 m = *(const float4*)(sH + ci);
            const float4 c = *(const float4*)(sH + ci + LSTRIDE);
            float4 o;
            o.x = (a.x + 2.f * m.x + c.x) * m16[k][0];
            o.y = (a.y + 2.f * m.y + c.y) * m16[k][1];
            o.z = (a.z + 2.f * m.z + c.z) * m16[k][2];
            o.w = (a.w + 2.f * m.w + c.w) * m16[k][3];
            if (s < STEPS - 1) {
                *(float4*)(sT + ci + LSTRIDE) = o;           // keep tile in LDS
                if ((ring3 >> k) & 1) {                      // export boundary ring
                    float2 lo; lo.x = o.x; lo.y = o.y;
                    float2 hi; hi.x = o.z; hi.y = o.w;
                    stc8(rcur + o3[k], lo);
                    stc8(rcur + o3[k] + 2, hi);
                }
            } else {
                *(float4*)(outb + o3[k]) = o;                // final: plain cached store
            }
        }
        if (s == STEPS - 1) break;

        // ---- flag barrier: no RMW, no shared-line contention ----
        __syncthreads();   // per-wave vmcnt(0) before s_barrier: ring stores acked @ LLC
        if (tid == 0)
            __hip_atomic_store(myflag, s + 1, __ATOMIC_RELAXED, __HIP_MEMORY_SCOPE_AGENT);
        if (tid < 64) {    // wave 0: each lane polls one batch flag (48 distinct lines)
            const int* f = (tid < BPB) ? (bflags + tid * FLAG_STRIDE) : nullptr;
            long long t0 = (long long)clock64();
            for (;;) {
                const int v = f ? __hip_atomic_load(f, __ATOMIC_RELAXED, __HIP_MEMORY_SCOPE_AGENT)
                               : 0x7fffffff;
                if (__all(v >= s + 1)) break;
                __builtin_amdgcn_s_sleep(1);
                if ((long long)clock64() - t0 > 200000000LL) break;  // no-hang bailout
            }
        }
        __syncthreads();

        // halo refresh from ring(s) buffer (sc1)
        const float* prev = (s & 1) ? outb : wsb;
        if (hgo >= 0) {
            const float2 lo = ldc8(prev + hgo);
            const float2 hi = ldc8(prev + hgo + 2);
            float4 v; v.x = lo.x; v.y = lo.y; v.z = hi.x; v.w = hi.y;
            *(float4*)(sT + hlo) = v;
        }
        __syncthreads();
    }
}

extern "C" void kernel_launch(void* const* d_in, const int* in_sizes, int n_in,
                              void* d_out, int out_size, void* d_ws, size_t ws_size,
                              hipStream_t stream)
{
    const float* T    = (const float*)d_in[0];
    const float* ug   = (const float*)d_in[1];
    const float* vg   = (const float*)d_in[2];
    const float* lat  = (const float*)d_in[3];
    const float* lon  = (const float*)d_in[4];
    const float* mask = (const float*)d_in[5];
    float* out = (float*)d_out;

    int*   flags = (int*)d_ws;                        // 8 x 48 flags @ 128 B stride
    float* wsf   = (float*)((char*)d_ws + 65536);     // even-step ring buffer (8.3 MB)

    hipMemsetAsync(d_ws, 0, 65536, stream);           // zero flags (capture-legal)

    ocean_persist<<<dim3(GX, GY, NB), dim3(256), 0, stream>>>(
        T, ug, vg, lat, lon, mask, out, wsf, flags);
}

// Round 8
// 217.233 us; speedup vs baseline: 4.9731x; 1.0963x over previous
//
#include <hip/hip_runtime.h>

#define H 360
#define W 720
#define NB 8
#define TX 120
#define TY 45
#define GX 6
#define GY 8
#define BPB 48
#define LST 132                 // LDS row stride (floats); window = 128 cols (halo 4)
#define DTS 600.0f
#define REARTH 6371000.0f
#define D2R 0.017453292519943295f

#define ROWS_T 53               // sT rows: gi = by-4+r (halo 4 top/bottom)
#define ROWS_H 51               // sH rows: h for sT rows 1..51 at index r-1
#define NQ1 (ROWS_T*32)         // 1696 preamble quads
#define NQ2 (ROWS_H*32)         // 1632 stage-2 quads (sT rows 1..51)
#define NQ3 (49*32)             // 1568 stage-3 quads (output sT rows 2..50)
#define NHALO 346               // rows {0..3,49..52}x32 + rows 4..48 x cols {0,124}
#define NPAIRS 10
#define FLAG_STRIDE 32          // 128 B per flag line

// LLC-coherent 8B load/store (agent-scope relaxed atomic -> dwordx2 sc1)
static __device__ __forceinline__ float2 ldc8(const float* p) {
    unsigned long long u = __hip_atomic_load((const unsigned long long*)p,
                                             __ATOMIC_RELAXED, __HIP_MEMORY_SCOPE_AGENT);
    return __builtin_bit_cast(float2, u);
}
static __device__ __forceinline__ void stc8(float* p, float2 v) {
    __hip_atomic_store((unsigned long long*)p, __builtin_bit_cast(unsigned long long, v),
                       __ATOMIC_RELAXED, __HIP_MEMORY_SCOPE_AGENT);
}

__global__ __launch_bounds__(256, 2) void ocean_persist(
    const float* __restrict__ Tin, const float* __restrict__ ug,
    const float* __restrict__ vg, const float* __restrict__ lat,
    const float* __restrict__ lon, const float* __restrict__ mask,
    float* __restrict__ out, float* __restrict__ wsf, int* __restrict__ flags)
{
    __shared__ float sT[ROWS_T * LST];
    __shared__ float sH[ROWS_H * LST];

    const int tid = threadIdx.x;
    const int b  = blockIdx.z;
    const int bx = blockIdx.x * TX;
    const int by = blockIdx.y * TY;
    const int plane = H * W;

    const float dlat = lat[1] - lat[0];               // -0.5
    const float dy   = REARTH * D2R * fabsf(dlat);
    const float sgn  = (dlat > 0.f) ? 1.f : -1.f;
    const float dlon = lon[1] - lon[0];
    const float i2dy = 0.5f / dy, i1dy = 1.f / dy;

    const float* Tb = Tin + b * plane;
    const float* ub = ug  + b * plane;
    const float* vb = vg  + b * plane;
    float* outb = out + b * plane;
    float* wsb  = wsf + b * plane;

    int* bflags = flags + b * BPB * FLAG_STRIDE;
    int* myflag = bflags + (blockIdx.y * GX + blockIdx.x) * FLAG_STRIDE;

    // ---------- bake invariants ----------
    // preamble quads
    int goff1[7], lds1o[7];
    #pragma unroll
    for (int k = 0; k < 7; ++k) {
        const int q = tid + 256 * k;
        if (q < NQ1) {
            const int r = q >> 5, c0 = (q & 31) << 2;
            int gi = by - 4 + r; gi = min(max(gi, 0), H - 1);
            const int gj = (bx - 4 + c0 + W) % W;    // quad stays contiguous
            goff1[k] = gi * W + gj;
            lds1o[k] = r * LST + c0;
        } else goff1[k] = -1;
    }

    // halo import quads (2/thread)
    int hgo[2], hlo[2];
    #pragma unroll
    for (int t = 0; t < 2; ++t) {
        const int q = tid + 256 * t;
        if (q < NHALO) {
            int r, c0;
            if (q < 256) { const int ri = q >> 5; r = (ri < 4) ? ri : 45 + ri; c0 = (q & 31) << 2; }
            else { const int u = q - 256; r = 4 + (u >> 1); c0 = (u & 1) ? 124 : 0; }
            int gi = by - 4 + r; gi = min(max(gi, 0), H - 1);
            const int gj = (bx - 4 + c0 + W) % W;
            hgo[t] = gi * W + gj;
            hlo[t] = r * LST + c0;
        } else hgo[t] = -1;
    }

    // stage-2 coeffs: wrapped gj (halo cols evolve as true cells); gi gates domain
    int ldsC[7];
    float cu[7][4], cv[7][4];
    unsigned dom = 0, hlz = 0, hrz = 0;
    #pragma unroll
    for (int k = 0; k < 7; ++k) {
        #pragma unroll
        for (int j = 0; j < 4; ++j) { cu[k][j] = 0.f; cv[k][j] = 0.f; }
        const int q = tid + 256 * k;
        if (q < NQ2) {
            const int r = 1 + (q >> 5), c0 = (q & 31) << 2;
            ldsC[k] = r * LST + c0;
            const int gi = by - 4 + r;
            const int gj0 = (bx - 4 + c0 + W) % W;   // multiple of 4; quad contiguous
            if ((unsigned)gi < H) {
                const float dxv  = REARTH * D2R * dlon * cosf(lat[gi] * D2R);
                const float rdx2 = 0.5f / dxv;
                const float ivy  = (gi == 0 || gi == H - 1) ? i1dy : i2dy;
                #pragma unroll
                for (int j = 0; j < 4; ++j) {
                    const int off = gi * W + gj0 + j;
                    const float mk = mask[off];
                    cu[k][j] = -DTS * mk * ub[off] * rdx2;
                    cv[k][j] = -DTS * mk * vb[off] * sgn * ivy;
                    dom |= 1u << (4 * k + j);
                }
            }
            if (gj0 == 0)         hlz |= 1u << k;    // filter zero-pad left of gj=0
            if (gj0 + 3 == W - 1) hrz |= 1u << k;    // filter zero-pad right of gj=W-1
        } else ldsC[k] = -1;
    }

    // stage-3 quads: output sT rows 2..50, all col quads
    int n3[7], o3[7];
    float m16[7][4];
    unsigned tilem = 0, ringm = 0;
    #pragma unroll
    for (int k = 0; k < 7; ++k) {
        const int q = tid + 256 * k;
        if (q < NQ3) {
            const int rr = 2 + (q >> 5), c0 = (q & 31) << 2;
            n3[k] = rr * LST + c0;
            const int gi = by - 4 + rr;
            const int gj0 = (bx - 4 + c0 + W) % W;
            #pragma unroll
            for (int j = 0; j < 4; ++j)
                m16[k][j] = ((unsigned)gi < H) ? mask[gi * W + gj0 + j] * (1.f / 16.f) : 0.f;
            const bool inTile = (rr >= 4 && rr <= 48 && c0 >= 4 && c0 <= 120);
            o3[k] = inTile ? (gi * W + bx + c0 - 4) : 0;
            if (inTile) {
                tilem |= 1u << k;
                if (rr <= 7 || rr >= 45 || c0 == 4 || c0 == 120) ringm |= 1u << k;
            }
        } else n3[k] = -1;
    }

    // ---------- preamble: full window -> sT ----------
    #pragma unroll
    for (int k = 0; k < 7; ++k)
        if (goff1[k] >= 0)
            *(float4*)(sT + lds1o[k]) = *(const float4*)(Tb + goff1[k]);
    __syncthreads();

    // stage-2: advection + horizontal 1-2-1 (with seam pad flags) -> sH
    auto stage2 = [&]() {
        #pragma unroll
        for (int k = 0; k < 7; ++k) {
            const bool act = (ldsC[k] >= 0);
            const int ci = act ? ldsC[k] : LST;
            const float4 vC = *(const float4*)(sT + ci);
            const float4 vU = *(const float4*)(sT + ci - LST);
            const float4 vD = *(const float4*)(sT + ci + LST);
            const float tl = __shfl_up(vC.w, 1);     // periodic: wrapped values in LDS
            const float tr = __shfl_down(vC.x, 1);
            float4 o;
            o.x = (((dom >> (4*k+0)) & 1) ? vC.x : 0.f) + cu[k][0]*(vC.y - tl)   + cv[k][0]*(vD.x - vU.x);
            o.y = (((dom >> (4*k+1)) & 1) ? vC.y : 0.f) + cu[k][1]*(vC.z - vC.x) + cv[k][1]*(vD.y - vU.y);
            o.z = (((dom >> (4*k+2)) & 1) ? vC.z : 0.f) + cu[k][2]*(vC.w - vC.y) + cv[k][2]*(vD.z - vU.z);
            o.w = (((dom >> (4*k+3)) & 1) ? vC.w : 0.f) + cu[k][3]*(tr   - vC.z) + cv[k][3]*(vD.w - vU.w);
            float hl = __shfl_up(o.w, 1);
            float hr = __shfl_down(o.x, 1);
            if ((hlz >> k) & 1) hl = 0.f;            // physical zero-pad at gj=-1
            if ((hrz >> k) & 1) hr = 0.f;            // physical zero-pad at gj=W
            float4 h;
            h.x = hl  + 2.f * o.x + o.y;
            h.y = o.x + 2.f * o.y + o.z;
            h.z = o.y + 2.f * o.z + o.w;
            h.w = o.z + 2.f * o.w + hr;
            if (act) *(float4*)(sH + ci - LST) = h;
        }
    };

    // ---------- 10 pairs of steps ----------
    #pragma unroll 1
    for (int p = 0; p < NPAIRS; ++p) {
        if (p) {
            __syncthreads();       // drains ring stores (vmcnt0 before s_barrier)
            if (tid == 0)
                __hip_atomic_store(myflag, p, __ATOMIC_RELAXED, __HIP_MEMORY_SCOPE_AGENT);
            if (tid < 64) {
                const int* f = (tid < BPB) ? (bflags + tid * FLAG_STRIDE) : nullptr;
                long long t0 = (long long)clock64();
                for (;;) {
                    const int v = f ? __hip_atomic_load(f, __ATOMIC_RELAXED, __HIP_MEMORY_SCOPE_AGENT)
                                   : 0x7fffffff;
                    if (__all(v >= p)) break;
                    __builtin_amdgcn_s_sleep(1);
                    if ((long long)clock64() - t0 > 200000000LL) break;
                }
            }
            __syncthreads();
            // halo import (depth 4) from pair p-1's ring buffer
            const float* prev = ((p - 1) & 1) ? outb : wsb;
            #pragma unroll
            for (int t = 0; t < 2; ++t) {
                if (hgo[t] >= 0) {
                    const float2 lo = ldc8(prev + hgo[t]);
                    const float2 hi = ldc8(prev + hgo[t] + 2);
                    float4 v; v.x = lo.x; v.y = lo.y; v.z = hi.x; v.w = hi.y;
                    *(float4*)(sT + hlo[t]) = v;
                }
            }
            __syncthreads();
        }

        // ===== sub-step A =====
        stage2();
        __syncthreads();
        #pragma unroll
        for (int k = 0; k < 7; ++k) {              // stage-3 A: write sT only
            if (n3[k] < 0) continue;
            const int ci = n3[k];
            const float4 a = *(const float4*)(sH + ci - 2 * LST);
            const float4 m = *(const float4*)(sH + ci - LST);
            const float4 c = *(const float4*)(sH + ci);
            float4 o;
            o.x = (a.x + 2.f * m.x + c.x) * m16[k][0];
            o.y = (a.y + 2.f * m.y + c.y) * m16[k][1];
            o.z = (a.z + 2.f * m.z + c.z) * m16[k][2];
            o.w = (a.w + 2.f * m.w + c.w) * m16[k][3];
            *(float4*)(sT + ci) = o;
        }
        __syncthreads();
        // edge-row replication for one-sided d/dy (clamp-trick invariant)
        if (blockIdx.y == 0 && tid < 32) {
            const int c0 = tid << 2;
            *(float4*)(sT + 3 * LST + c0) = *(const float4*)(sT + 4 * LST + c0);
        }
        if (blockIdx.y == GY - 1 && tid < 32) {
            const int c0 = tid << 2;
            *(float4*)(sT + 49 * LST + c0) = *(const float4*)(sT + 48 * LST + c0);
        }
        __syncthreads();

        // ===== sub-step B =====
        stage2();
        __syncthreads();
        if (p < NPAIRS - 1) {
            float* rcur = (p & 1) ? outb : wsb;    // ring(pair p) -> buf[p&1]
            #pragma unroll
            for (int k = 0; k < 7; ++k) {
                if (n3[k] < 0) continue;
                const int ci = n3[k];
                const float4 a = *(const float4*)(sH + ci - 2 * LST);
                const float4 m = *(const float4*)(sH + ci - LST);
                const float4 c = *(const float4*)(sH + ci);
                float4 o;
                o.x = (a.x + 2.f * m.x + c.x) * m16[k][0];
                o.y = (a.y + 2.f * m.y + c.y) * m16[k][1];
                o.z = (a.z + 2.f * m.z + c.z) * m16[k][2];
                o.w = (a.w + 2.f * m.w + c.w) * m16[k][3];
                *(float4*)(sT + ci) = o;
                if ((ringm >> k) & 1) {
                    float2 lo; lo.x = o.x; lo.y = o.y;
                    float2 hi; hi.x = o.z; hi.y = o.w;
                    stc8(rcur + o3[k], lo);
                    stc8(rcur + o3[k] + 2, hi);
                }
            }
        } else {
            #pragma unroll
            for (int k = 0; k < 7; ++k) {          // final: tile -> out (cached)
                if (n3[k] < 0 || !((tilem >> k) & 1)) continue;
                const int ci = n3[k];
                const float4 a = *(const float4*)(sH + ci - 2 * LST);
                const float4 m = *(const float4*)(sH + ci - LST);
                const float4 c = *(const float4*)(sH + ci);
                float4 o;
                o.x = (a.x + 2.f * m.x + c.x) * m16[k][0];
                o.y = (a.y + 2.f * m.y + c.y) * m16[k][1];
                o.z = (a.z + 2.f * m.z + c.z) * m16[k][2];
                o.w = (a.w + 2.f * m.w + c.w) * m16[k][3];
                *(float4*)(outb + o3[k]) = o;
            }
        }
    }
}

extern "C" void kernel_launch(void* const* d_in, const int* in_sizes, int n_in,
                              void* d_out, int out_size, void* d_ws, size_t ws_size,
                              hipStream_t stream)
{
    const float* T    = (const float*)d_in[0];
    const float* ug   = (const float*)d_in[1];
    const float* vg   = (const float*)d_in[2];
    const float* lat  = (const float*)d_in[3];
    const float* lon  = (const float*)d_in[4];
    const float* mask = (const float*)d_in[5];
    float* out = (float*)d_out;

    int*   flags = (int*)d_ws;                        // 8 x 48 flags @ 128 B
    float* wsf   = (float*)((char*)d_ws + 65536);     // even-pair ring buffer

    hipMemsetAsync(d_ws, 0, 65536, stream);

    ocean_persist<<<dim3(GX, GY, NB), dim3(256), 0, stream>>>(
        T, ug, vg, lat, lon, mask, out, wsf, flags);
}

// Round 9
// 144.275 us; speedup vs baseline: 7.4879x; 1.5057x over previous
//
#include <hip/hip_runtime.h>

#define H 360
#define W 720
#define NB 8
#define TX 120
#define TY 45
#define GX 6
#define GY 8
#define LST 132                 // LDS row stride (floats); window = 128 cols (halo 4)
#define DTS 600.0f
#define REARTH 6371000.0f
#define D2R 0.017453292519943295f

#define ROWS_T 53               // sT rows: gi = by-4+r (halo 4)
#define NQ1 (ROWS_T*32)         // 1696 preamble quads
#define NHALO 346               // rows {0..3,49..52}x32 + rows 4..48 x cols {0,124}
#define NPAIRS 10
#define FLAG_STRIDE 32          // 128 B per flag line

// LLC-coherent 8B load/store (agent-scope relaxed atomic -> dwordx2 sc1)
static __device__ __forceinline__ float2 ldc8(const float* p) {
    unsigned long long u = __hip_atomic_load((const unsigned long long*)p,
                                             __ATOMIC_RELAXED, __HIP_MEMORY_SCOPE_AGENT);
    return __builtin_bit_cast(float2, u);
}
static __device__ __forceinline__ void stc8(float* p, float2 v) {
    __hip_atomic_store((unsigned long long*)p, __builtin_bit_cast(unsigned long long, v),
                       __ATOMIC_RELAXED, __HIP_MEMORY_SCOPE_AGENT);
}

__global__ __launch_bounds__(256, 2) void ocean_persist(
    const float* __restrict__ Tin, const float* __restrict__ ug,
    const float* __restrict__ vg, const float* __restrict__ lat,
    const float* __restrict__ lon, const float* __restrict__ mask,
    float* __restrict__ out, float* __restrict__ wsf, int* __restrict__ flags)
{
    __shared__ float sT[ROWS_T * LST];   // persistent T window
    __shared__ float sHB[14 * LST];      // h boundary rows: slot (rg-1)*2+{0,1} = rg's first 2 h rows

    const int tid = threadIdx.x;
    const int b  = blockIdx.z;
    const int bx = blockIdx.x * TX;
    const int by = blockIdx.y * TY;
    const int plane = H * W;

    const float dlat = lat[1] - lat[0];               // -0.5
    const float dy   = REARTH * D2R * fabsf(dlat);
    const float sgn  = (dlat > 0.f) ? 1.f : -1.f;
    const float dlon = lon[1] - lon[0];
    const float i2dy = 0.5f / dy, i1dy = 1.f / dy;

    const float* Tb = Tin + b * plane;
    const float* ub = ug  + b * plane;
    const float* vb = vg  + b * plane;
    float* outb = out + b * plane;
    float* wsb  = wsf + b * plane;

    int* bflags = flags + b * (GX * GY) * FLAG_STRIDE;
    int* myflag = bflags + (blockIdx.y * GX + blockIdx.x) * FLAG_STRIDE;

    // ---------- strip mapping ----------
    const int cq = tid & 31;             // col-quad 0..31
    const int rg = tid >> 5;             // row-group 0..7
    const int c0 = cq << 2;
    const int a  = 1 + 7 * rg;           // first h row (sT row index); rg7 -> 50
    const int cnt = (rg < 7) ? 7 : 2;    // h rows owned
    const int gj0 = (bx - 4 + c0 + W) % W;
    const bool hlzb = (gj0 == 0);            // physical zero-pad left of gj=0
    const bool hrzb = (gj0 + 3 == W - 1);    // physical zero-pad right of gj=W-1
    const bool topB = (blockIdx.y == 0), botB = (blockIdx.y == GY - 1);

    // ---------- bake invariants ----------
    int goff1[7], lds1o[7];              // preamble quads
    #pragma unroll
    for (int k = 0; k < 7; ++k) {
        const int q = tid + 256 * k;
        if (q < NQ1) {
            const int r = q >> 5, cc0 = (q & 31) << 2;
            int gi = by - 4 + r; gi = min(max(gi, 0), H - 1);
            const int gj = (bx - 4 + cc0 + W) % W;
            goff1[k] = gi * W + gj;
            lds1o[k] = r * LST + cc0;
        } else goff1[k] = -1;
    }

    int hgo[2], hlo[2];                  // halo import quads (2/thread)
    #pragma unroll
    for (int t = 0; t < 2; ++t) {
        const int q = tid + 256 * t;
        if (q < NHALO) {
            int r, cc0;
            if (q < 256) { const int ri = q >> 5; r = (ri < 4) ? ri : 45 + ri; cc0 = (q & 31) << 2; }
            else { const int u = q - 256; r = 4 + (u >> 1); cc0 = (u & 1) ? 124 : 0; }
            int gi = by - 4 + r; gi = min(max(gi, 0), H - 1);
            const int gj = (bx - 4 + cc0 + W) % W;
            hgo[t] = gi * W + gj;
            hlo[t] = r * LST + cc0;
        } else hgo[t] = -1;
    }

    // advection coeffs for own h rows a..a+cnt-1
    float cuA[7][4], cvA[7][4];
    unsigned domm = 0;
    #pragma unroll
    for (int j = 0; j < 7; ++j) {
        #pragma unroll
        for (int t = 0; t < 4; ++t) { cuA[j][t] = 0.f; cvA[j][t] = 0.f; }
        if (j < cnt) {
            const int gi = by - 4 + a + j;
            if ((unsigned)gi < H) {
                const float dxv  = REARTH * D2R * dlon * cosf(lat[gi] * D2R);
                const float rdx2 = 0.5f / dxv;
                const float ivy  = (gi == 0 || gi == H - 1) ? i1dy : i2dy;
                #pragma unroll
                for (int t = 0; t < 4; ++t) {
                    const int off = gi * W + gj0 + t;
                    const float mk = mask[off];
                    cuA[j][t] = -DTS * mk * ub[off] * rdx2;
                    cvA[j][t] = -DTS * mk * vb[off] * sgn * ivy;
                }
                domm |= 1u << j;
            }
        }
    }

    // out rows n = 2+7rg+i (rg<7 only)
    float m16A[7][4];
    int o3A[7];
    unsigned tilem = 0, ringm = 0;
    #pragma unroll
    for (int i = 0; i < 7; ++i) {
        #pragma unroll
        for (int t = 0; t < 4; ++t) m16A[i][t] = 0.f;
        o3A[i] = 0;
        if (rg < 7) {
            const int n = 2 + 7 * rg + i;
            const int gi = by - 4 + n;
            if ((unsigned)gi < H) {
                #pragma unroll
                for (int t = 0; t < 4; ++t)
                    m16A[i][t] = mask[gi * W + gj0 + t] * (1.f / 16.f);
            }
            const bool inTile = (n >= 4 && n <= 48 && cq >= 1 && cq <= 30);
            if (inTile) {
                o3A[i] = gi * W + bx + c0 - 4;
                tilem |= 1u << i;
                if (n <= 7 || n >= 45 || cq == 1 || cq == 30) ringm |= 1u << i;
            }
        }
    }

    // neighbor flag pointers (8 neighbors; out-of-H -> self, trivially done)
    const int* nbrF = myflag;
    if (tid < 8) {
        int dyn, dxn;
        if (tid < 3)      { dyn = -1; dxn = tid - 1; }
        else if (tid == 3){ dyn = 0;  dxn = -1; }
        else if (tid == 4){ dyn = 0;  dxn = 1; }
        else              { dyn = 1;  dxn = tid - 6; }
        const int ny = (int)blockIdx.y + dyn;
        const int nx = ((int)blockIdx.x + dxn + GX) % GX;
        if (ny >= 0 && ny < GY) nbrF = bflags + (ny * GX + nx) * FLAG_STRIDE;
    }

    // ---------- preamble: full window -> sT ----------
    #pragma unroll
    for (int k = 0; k < 7; ++k)
        if (goff1[k] >= 0)
            *(float4*)(sT + lds1o[k]) = *(const float4*)(Tb + goff1[k]);
    __syncthreads();

    // ---------- one substep (advection + separable filter), strip version ----
    auto substep = [&](bool isA, bool writeST, float* rcur, bool finalOut) {
        float4 hA[7];
        // rolling 3-row window over sT
        float4 m1 = *(const float4*)(sT + (a - 1) * LST + c0);
        float4 cc = *(const float4*)(sT + a * LST + c0);
        #pragma unroll
        for (int j = 0; j < 7; ++j) {
            if (j < cnt) {
                const float4 vU = m1, vC = cc;
                const float4 vD = *(const float4*)(sT + (a + j + 1) * LST + c0);
                const float tl = __shfl_up(vC.w, 1);    // col c0-1 (garbage -> window col 0 only)
                const float tr = __shfl_down(vC.x, 1);  // col c0+4 (garbage -> window col 127 only)
                const bool dj = (domm >> j) & 1;
                float4 o;
                o.x = (dj ? vC.x : 0.f) + cuA[j][0]*(vC.y - tl)   + cvA[j][0]*(vD.x - vU.x);
                o.y = (dj ? vC.y : 0.f) + cuA[j][1]*(vC.z - vC.x) + cvA[j][1]*(vD.y - vU.y);
                o.z = (dj ? vC.z : 0.f) + cuA[j][2]*(vC.w - vC.y) + cvA[j][2]*(vD.z - vU.z);
                o.w = (dj ? vC.w : 0.f) + cuA[j][3]*(tr   - vC.z) + cvA[j][3]*(vD.w - vU.w);
                float hl = __shfl_up(o.w, 1);
                float hr = __shfl_down(o.x, 1);
                if (hlzb) hl = 0.f;
                if (hrzb) hr = 0.f;
                hA[j].x = hl  + 2.f * o.x + o.y;
                hA[j].y = o.x + 2.f * o.y + o.z;
                hA[j].z = o.y + 2.f * o.z + o.w;
                hA[j].w = o.z + 2.f * o.w + hr;
                m1 = cc; cc = vD;
            }
        }
        // publish first two h rows for the group below
        if (rg >= 1) {
            *(float4*)(sHB + ((rg - 1) * 2)     * LST + c0) = hA[0];
            *(float4*)(sHB + ((rg - 1) * 2 + 1) * LST + c0) = hA[1];
        }
        __syncthreads();
        // out phase: vertical 1-2-1 from registers (+2 sHB rows), write sT/export
        if (rg < 7) {
            const float4 hb0 = *(const float4*)(sHB + (2 * rg)     * LST + c0);
            const float4 hb1 = *(const float4*)(sHB + (2 * rg + 1) * LST + c0);
            float4 sA = {0,0,0,0}, sB = {0,0,0,0};
            #pragma unroll
            for (int i = 0; i < 7; ++i) {
                const float4 hm = hA[i];
                const float4 hc = (i < 6) ? hA[i + 1] : hb0;
                const float4 hp = (i < 5) ? hA[i + 2] : ((i == 5) ? hb0 : hb1);
                float4 o;
                o.x = (hm.x + 2.f * hc.x + hp.x) * m16A[i][0];
                o.y = (hm.y + 2.f * hc.y + hp.y) * m16A[i][1];
                o.z = (hm.z + 2.f * hc.z + hp.z) * m16A[i][2];
                o.w = (hm.w + 2.f * hc.w + hp.w) * m16A[i][3];
                if (writeST) *(float4*)(sT + (2 + 7 * rg + i) * LST + c0) = o;
                if (isA && i == 2) sA = o;   // row 4 value (top replica source)
                if (isA && i == 4) sB = o;   // row 48 value (bottom replica source)
                if (rcur && ((ringm >> i) & 1)) {
                    float2 lo; lo.x = o.x; lo.y = o.y;
                    float2 hi; hi.x = o.z; hi.y = o.w;
                    stc8(rcur + o3A[i], lo);
                    stc8(rcur + o3A[i] + 2, hi);
                }
                if (finalOut && ((tilem >> i) & 1))
                    *(float4*)(outb + o3A[i]) = o;
            }
            // clamp-replica patches between sub-steps (one-sided d/dy invariant)
            if (isA && topB && rg == 0) *(float4*)(sT + 3 * LST + c0)  = sA;
            if (isA && botB && rg == 6) *(float4*)(sT + 49 * LST + c0) = sB;
        }
        __syncthreads();
    };

    // ---------- 10 pairs of steps ----------
    #pragma unroll 1
    for (int p = 0; p < NPAIRS; ++p) {
        if (p) {
            __syncthreads();   // drains ring stores (per-wave vmcnt0 before s_barrier)
            if (tid == 0)
                __hip_atomic_store(myflag, p, __ATOMIC_RELAXED, __HIP_MEMORY_SCOPE_AGENT);
            if (tid < 64) {    // neighbor-only poll: lanes 0..7 watch the 8 neighbors
                long long t0 = (long long)clock64();
                for (;;) {
                    const int v = (tid < 8)
                        ? __hip_atomic_load(nbrF, __ATOMIC_RELAXED, __HIP_MEMORY_SCOPE_AGENT)
                        : 0x7fffffff;
                    if (__all(v >= p)) break;
                    __builtin_amdgcn_s_sleep(1);
                    if ((long long)clock64() - t0 > 200000000LL) break;  // no-hang bailout
                }
            }
            __syncthreads();
            // halo import (depth 4) from pair p-1's ring buffer
            const float* prev = ((p - 1) & 1) ? outb : wsb;
            #pragma unroll
            for (int t = 0; t < 2; ++t) {
                if (hgo[t] >= 0) {
                    const float2 lo = ldc8(prev + hgo[t]);
                    const float2 hi = ldc8(prev + hgo[t] + 2);
                    float4 v; v.x = lo.x; v.y = lo.y; v.z = hi.x; v.w = hi.y;
                    *(float4*)(sT + hlo[t]) = v;
                }
            }
            __syncthreads();
        }

        const bool last = (p == NPAIRS - 1);
        float* rcur = (p & 1) ? outb : wsb;        // ring(pair p) buffer
        substep(true,  true,       nullptr,             false);   // sub-step A
        substep(false, !last,      last ? nullptr : rcur, last);  // sub-step B
    }
}

extern "C" void kernel_launch(void* const* d_in, const int* in_sizes, int n_in,
                              void* d_out, int out_size, void* d_ws, size_t ws_size,
                              hipStream_t stream)
{
    const float* T    = (const float*)d_in[0];
    const float* ug   = (const float*)d_in[1];
    const float* vg   = (const float*)d_in[2];
    const float* lat  = (const float*)d_in[3];
    const float* lon  = (const float*)d_in[4];
    const float* mask = (const float*)d_in[5];
    float* out = (float*)d_out;

    int*   flags = (int*)d_ws;                        // 8 x 48 flags @ 128 B
    float* wsf   = (float*)((char*)d_ws + 65536);     // even-pair ring buffer

    hipMemsetAsync(d_ws, 0, 65536, stream);

    ocean_persist<<<dim3(GX, GY, NB), dim3(256), 0, stream>>>(
        T, ug, vg, lat, lon, mask, out, wsf, flags);
}

// Round 10
// 141.212 us; speedup vs baseline: 7.6503x; 1.0217x over previous
//
#include <hip/hip_runtime.h>

#define H 360
#define W 720
#define NB 8
#define XC 3
#define YC 10
#define TX 240
#define TY 36
#define BPB (XC*YC)             // 30 blocks per batch
#define WR 52                   // window rows: gi = by-8+r, r in 0..51
#define LST 260                 // LDS row stride (floats): 256 cols + 4 pad
#define DTS 600.0f
#define REARTH 6371000.0f
#define D2R 0.017453292519943295f

#define NQ1 (WR*64)             // 3328 preamble quads
#define NHALO 1168              // rows{0..7,44..51}x64 + rows 8..43 x quads{0,1,62,63}
#define NGROUPS 5               // 5 groups x 4 substeps = 20 steps
#define FLAG_STRIDE 32          // 128 B per flag line

// LLC-coherent 8B load/store (agent-scope relaxed atomic -> dwordx2 sc1)
static __device__ __forceinline__ float2 ldc8(const float* p) {
    unsigned long long u = __hip_atomic_load((const unsigned long long*)p,
                                             __ATOMIC_RELAXED, __HIP_MEMORY_SCOPE_AGENT);
    return __builtin_bit_cast(float2, u);
}
static __device__ __forceinline__ void stc8(float* p, float2 v) {
    __hip_atomic_store((unsigned long long*)p, __builtin_bit_cast(unsigned long long, v),
                       __ATOMIC_RELAXED, __HIP_MEMORY_SCOPE_AGENT);
}

__global__ __launch_bounds__(512, 2) void ocean_persist(
    const float* __restrict__ Tin, const float* __restrict__ ug,
    const float* __restrict__ vg, const float* __restrict__ lat,
    const float* __restrict__ lon, const float* __restrict__ mask,
    float* __restrict__ out, float* __restrict__ wsf, int* __restrict__ flags)
{
    __shared__ float sT[WR * LST];       // the ONLY LDS buffer (54 KB)

    const int tid = threadIdx.x;
    const int b  = blockIdx.z;
    const int bx = blockIdx.x * TX;
    const int by = blockIdx.y * TY;
    const int plane = H * W;

    const float dlat = lat[1] - lat[0];               // -0.5
    const float dy   = REARTH * D2R * fabsf(dlat);
    const float sgn  = (dlat > 0.f) ? 1.f : -1.f;
    const float dlon = lon[1] - lon[0];
    const float i2dy = 0.5f / dy, i1dy = 1.f / dy;

    const float* Tb = Tin + b * plane;
    const float* ub = ug  + b * plane;
    const float* vb = vg  + b * plane;
    float* outb = out + b * plane;
    float* wsb  = wsf + b * plane;

    int* bflags = flags + b * BPB * FLAG_STRIDE;
    int* myflag = bflags + (blockIdx.y * XC + blockIdx.x) * FLAG_STRIDE;

    // ---------- strip mapping: wave = row-group ----------
    const int cq = tid & 63;             // col quad 0..63 (window cols 0..255)
    const int rg = tid >> 6;             // row group 0..7 (== wave id)
    const int c0 = cq << 2;
    const int a  = 1 + 6 * rg;           // first h row (sT row index); h rows a..a+7
    const int gj0 = (bx - 8 + c0 + W) % W;
    const bool hlzb = (gj0 == 0);            // filter zero-pad left of gj=0
    const bool hrzb = (gj0 + 3 == W - 1);    // filter zero-pad right of gj=W-1
    const bool topB = (blockIdx.y == 0), botB = (blockIdx.y == YC - 1);

    // ---------- bake invariants ----------
    int goff1[7], lds1o[7];              // preamble quads
    #pragma unroll
    for (int k = 0; k < 7; ++k) {
        const int q = tid + 512 * k;
        if (q < NQ1) {
            const int r = q >> 6, cc0 = (q & 63) << 2;
            int gi = by - 8 + r; gi = min(max(gi, 0), H - 1);
            const int gj = (bx - 8 + cc0 + W) % W;
            goff1[k] = gi * W + gj;
            lds1o[k] = r * LST + cc0;
        } else goff1[k] = -1;
    }

    int hgo[3], hlo[3];                  // halo import quads (3/thread)
    #pragma unroll
    for (int t = 0; t < 3; ++t) {
        const int q = tid + 512 * t;
        if (q < NHALO) {
            int r, cc0;
            if (q < 1024) { const int ri = q >> 6; r = (ri < 8) ? ri : 36 + ri; cc0 = (q & 63) << 2; }
            else { const int u = q - 1024; r = 8 + (u >> 2); const int qi = u & 3;
                   cc0 = (qi < 2) ? (qi << 2) : (248 + ((qi - 2) << 2)); }
            int gi = by - 8 + r; gi = min(max(gi, 0), H - 1);
            const int gj = (bx - 8 + cc0 + W) % W;
            hgo[t] = gi * W + gj;
            hlo[t] = r * LST + cc0;
        } else hgo[t] = -1;
    }

    // advection coeffs for own 8 h rows (wrapped gj -> halo cols evolve truly)
    float cuA[8][4], cvA[8][4];
    unsigned domm = 0;
    #pragma unroll
    for (int j = 0; j < 8; ++j) {
        #pragma unroll
        for (int t = 0; t < 4; ++t) { cuA[j][t] = 0.f; cvA[j][t] = 0.f; }
        const int gi = by - 8 + a + j;
        if ((unsigned)gi < H) {
            const float dxv  = REARTH * D2R * dlon * cosf(lat[gi] * D2R);
            const float rdx2 = 0.5f / dxv;
            const float ivy  = (gi == 0 || gi == H - 1) ? i1dy : i2dy;
            #pragma unroll
            for (int t = 0; t < 4; ++t) {
                const int off = gi * W + gj0 + t;
                const float mk = mask[off];
                cuA[j][t] = -DTS * mk * ub[off] * rdx2;
                cvA[j][t] = -DTS * mk * vb[off] * sgn * ivy;
            }
            domm |= 1u << j;
        }
    }

    // out rows n = 2+6rg+i, i = 0..5
    float m16A[6][4];
    int o3A[6];
    unsigned outm = 0, tilem = 0, ringm = 0;
    #pragma unroll
    for (int i = 0; i < 6; ++i) {
        const int n = 2 + 6 * rg + i;
        const int gi = by - 8 + n;
        o3A[i] = 0;
        #pragma unroll
        for (int t = 0; t < 4; ++t)
            m16A[i][t] = ((unsigned)gi < H) ? mask[gi * W + gj0 + t] * (1.f / 16.f) : 0.f;
        if ((unsigned)gi < H) outm |= 1u << i;    // write sT (in-domain rows only)
        const bool inTile = (n >= 8 && n <= 43 && cq >= 2 && cq <= 61);
        if (inTile) {
            o3A[i] = gi * W + bx + c0 - 8;
            tilem |= 1u << i;
            if (n <= 15 || n >= 36 || cq <= 3 || cq >= 60) ringm |= 1u << i;
        }
    }

    // neighbor flag pointers (8-neighborhood; x wraps, y clamps to self)
    const int* nbrF = myflag;
    if (tid < 8) {
        int dyn, dxn;
        if (tid < 3)      { dyn = -1; dxn = tid - 1; }
        else if (tid == 3){ dyn = 0;  dxn = -1; }
        else if (tid == 4){ dyn = 0;  dxn = 1; }
        else              { dyn = 1;  dxn = tid - 6; }
        const int ny = (int)blockIdx.y + dyn;
        const int nx = ((int)blockIdx.x + dxn + XC) % XC;
        if (ny >= 0 && ny < YC) nbrF = bflags + (ny * XC + nx) * FLAG_STRIDE;
    }

    // ---------- preamble: full window -> sT ----------
    #pragma unroll
    for (int k = 0; k < 7; ++k)
        if (goff1[k] >= 0)
            *(float4*)(sT + lds1o[k]) = *(const float4*)(Tb + goff1[k]);
    __syncthreads();

    // ---------- one substep: pure-register vertical pass ----------
    auto substep = [&](bool finalOut, float* ring) {
        float4 hA[8];
        float4 m1 = *(const float4*)(sT + (a - 1) * LST + c0);
        float4 cc = *(const float4*)(sT + a * LST + c0);
        #pragma unroll
        for (int j = 0; j < 8; ++j) {
            const float4 vD = *(const float4*)(sT + (a + j + 1) * LST + c0);
            const float tl = __shfl_up(cc.w, 1);    // garbage only at cq=0 -> col 0 (unconsumed)
            const float tr = __shfl_down(cc.x, 1);  // garbage only at cq=63 -> col 255
            const bool dj = (domm >> j) & 1;
            float4 o;
            o.x = (dj ? cc.x : 0.f) + cuA[j][0]*(cc.y - tl)   + cvA[j][0]*(vD.x - m1.x);
            o.y = (dj ? cc.y : 0.f) + cuA[j][1]*(cc.z - cc.x) + cvA[j][1]*(vD.y - m1.y);
            o.z = (dj ? cc.z : 0.f) + cuA[j][2]*(cc.w - cc.y) + cvA[j][2]*(vD.z - m1.z);
            o.w = (dj ? cc.w : 0.f) + cuA[j][3]*(tr   - cc.z) + cvA[j][3]*(vD.w - m1.w);
            float hl = __shfl_up(o.w, 1);
            float hr = __shfl_down(o.x, 1);
            if (hlzb) hl = 0.f;
            if (hrzb) hr = 0.f;
            hA[j].x = hl  + 2.f * o.x + o.y;
            hA[j].y = o.x + 2.f * o.y + o.z;
            hA[j].z = o.y + 2.f * o.z + o.w;
            hA[j].w = o.z + 2.f * o.w + hr;
            m1 = cc; cc = vD;
        }
        __syncthreads();     // all stage-2 reads done before any sT write
        #pragma unroll
        for (int i = 0; i < 6; ++i) {
            const float4 hm = hA[i], hc = hA[i + 1], hp = hA[i + 2];
            float4 o;
            o.x = (hm.x + 2.f * hc.x + hp.x) * m16A[i][0];
            o.y = (hm.y + 2.f * hc.y + hp.y) * m16A[i][1];
            o.z = (hm.z + 2.f * hc.z + hp.z) * m16A[i][2];
            o.w = (hm.w + 2.f * hc.w + hp.w) * m16A[i][3];
            if (!finalOut) {
                if ((outm >> i) & 1)
                    *(float4*)(sT + (2 + 6 * rg + i) * LST + c0) = o;
                // clamp-replica patches (unique writers: edge rows suppressed above)
                if (topB && rg == 1 && i == 0) *(float4*)(sT + 7  * LST + c0) = o;  // row7 <- n=8
                if (botB && rg == 6 && i == 5) *(float4*)(sT + 44 * LST + c0) = o;  // row44 <- n=43
            } else if ((tilem >> i) & 1) {
                *(float4*)(outb + o3A[i]) = o;
            }
            if (ring && ((ringm >> i) & 1)) {
                float2 lo; lo.x = o.x; lo.y = o.y;
                float2 hi; hi.x = o.z; hi.y = o.w;
                stc8(ring + o3A[i], lo);
                stc8(ring + o3A[i] + 2, hi);
            }
        }
        __syncthreads();
    };

    // ---------- 5 groups x 4 substeps ----------
    #pragma unroll 1
    for (int g = 0; g < NGROUPS; ++g) {
        if (g) {
            __syncthreads();   // drains ring stores (per-wave vmcnt0 before s_barrier)
            if (tid == 0)
                __hip_atomic_store(myflag, g, __ATOMIC_RELAXED, __HIP_MEMORY_SCOPE_AGENT);
            if (tid < 64) {    // wave 0, lanes 0..7 poll the 8 neighbors
                long long t0 = (long long)clock64();
                for (;;) {
                    const int v = (tid < 8)
                        ? __hip_atomic_load(nbrF, __ATOMIC_RELAXED, __HIP_MEMORY_SCOPE_AGENT)
                        : 0x7fffffff;
                    if (__all(v >= g)) break;
                    __builtin_amdgcn_s_sleep(1);
                    if ((long long)clock64() - t0 > 200000000LL) break;  // no-hang bailout
                }
            }
            __syncthreads();
            // halo import (depth 8) from ring(g-1): g-1 even -> outb, odd -> wsb
            const float* prev = ((g - 1) & 1) ? wsb : outb;
            #pragma unroll
            for (int t = 0; t < 3; ++t) {
                if (hgo[t] >= 0) {
                    const float2 lo = ldc8(prev + hgo[t]);
                    const float2 hi = ldc8(prev + hgo[t] + 2);
                    float4 v; v.x = lo.x; v.y = lo.y; v.z = hi.x; v.w = hi.y;
                    *(float4*)(sT + hlo[t]) = v;
                }
            }
            __syncthreads();
        }
        const bool lastG = (g == NGROUPS - 1);
        float* ring = lastG ? nullptr : ((g & 1) ? wsb : outb);   // ring(g)
        substep(false, nullptr);
        substep(false, nullptr);
        substep(false, nullptr);
        substep(lastG, ring);            // 4th substep: export ring / final tile
    }
}

extern "C" void kernel_launch(void* const* d_in, const int* in_sizes, int n_in,
                              void* d_out, int out_size, void* d_ws, size_t ws_size,
                              hipStream_t stream)
{
    const float* T    = (const float*)d_in[0];
    const float* ug   = (const float*)d_in[1];
    const float* vg   = (const float*)d_in[2];
    const float* lat  = (const float*)d_in[3];
    const float* lon  = (const float*)d_in[4];
    const float* mask = (const float*)d_in[5];
    float* out = (float*)d_out;

    int*   flags = (int*)d_ws;                        // 8 x 30 flags @ 128 B
    float* wsf   = (float*)((char*)d_ws + 65536);     // odd-group ring buffer

    hipMemsetAsync(d_ws, 0, 65536, stream);

    ocean_persist<<<dim3(XC, YC, NB), dim3(512), 0, stream>>>(
        T, ug, vg, lat, lon, mask, out, wsf, flags);
}